// Round 4
// baseline (200.782 us; speedup 1.0000x reference)
//
#include <hip/hip_runtime.h>
#include <math.h>

typedef float f32x2 __attribute__((ext_vector_type(2)));

#define N_SMPS 16384
#define N_FCNS 2048
#define D_IN 32
#define D_OUT 32
#define KNN 4

// ---------------- Kernel 1: per-split top-4 ----------------------------------
// Block = 1024 threads = 16 waves; ONE LANE = ONE SAMPLE (no intra-block merge).
// All 16 waves stream the SAME 128-center split (16 KB) in the same order ->
// lead wave warms L1, rest hit L1. Centers delivered via uniform-address
// vector loads (register double-buffer), zero LDS in the hot loop.
// Grid = 16 sample-groups x 16 center-splits = 256 blocks (4 waves/SIMD).
#define K1_BLOCK 1024
#define G_C 16
#define C_PER (N_FCNS / G_C)   // 128 centers per split

__global__ __launch_bounds__(K1_BLOCK, 4) void k_topk(
    const float* __restrict__ x, const float* __restrict__ ctrs,
    float4* __restrict__ cu, int4* __restrict__ ci)
{
  __shared__ float s_hcsq[C_PER];
  const int tid = threadIdx.x;
  const int sp = blockIdx.x & (G_C - 1);
  const int sg = blockIdx.x >> 4;
  const int jbase = sp * C_PER;
  const int s = sg * K1_BLOCK + tid;

  // 0.5*||c||^2 for this split (also warms L1 with the split's rows)
  if (tid < C_PER) {
    const float4* cp4 = (const float4*)(ctrs + (size_t)(jbase + tid) * D_IN);
    float a = 0.f;
    #pragma unroll
    for (int q = 0; q < 8; ++q) {
      float4 v = cp4[q];
      a += v.x * v.x + v.y * v.y + v.z * v.z + v.w * v.w;
    }
    s_hcsq[tid] = 0.5f * a;
  }
  __syncthreads();

  // sample row as 16 packed float2 (for v_pk_fma_f32)
  f32x2 xr[16];
  {
    const float4* xp = (const float4*)(x + (size_t)s * D_IN);
    #pragma unroll
    for (int q = 0; q < 8; ++q) {
      float4 v = xp[q];
      f32x2 e0 = {v.x, v.y}; f32x2 e1 = {v.z, v.w};
      xr[2 * q] = e0; xr[2 * q + 1] = e1;
    }
  }

  const float4* crow = (const float4*)(ctrs + (size_t)jbase * D_IN);

  float u0 = -INFINITY, u1 = -INFINITY, u2 = -INFINITY, u3 = -INFINITY;
  int   i0 = -1, i1 = -1, i2 = -1, i3 = -1;

  // register double-buffer: rows t (cb0) and t+1 (cb1) resident
  float4 cb0[8], cb1[8];
  #pragma unroll
  for (int q = 0; q < 8; ++q) cb0[q] = crow[q];
  #pragma unroll
  for (int q = 0; q < 8; ++q) cb1[q] = crow[8 + q];

  for (int t = 0; t < C_PER; t += 2) {
    // ---- center t from cb0 ----
    {
      f32x2 a0 = 0.f, a1 = 0.f, a2 = 0.f, a3 = 0.f;
      #pragma unroll
      for (int q = 0; q < 8; ++q) {
        f32x2 c0 = {cb0[q].x, cb0[q].y};
        f32x2 c1 = {cb0[q].z, cb0[q].w};
        if (q & 1) {
          a2 = __builtin_elementwise_fma(xr[2 * q], c0, a2);
          a3 = __builtin_elementwise_fma(xr[2 * q + 1], c1, a3);
        } else {
          a0 = __builtin_elementwise_fma(xr[2 * q], c0, a0);
          a1 = __builtin_elementwise_fma(xr[2 * q + 1], c1, a1);
        }
      }
      f32x2 sA = a0 + a1, sB = a2 + a3, sT = sA + sB;
      const float acc = sT.x + sT.y - s_hcsq[t];
      const int j = jbase + t;
      if (acc > u3) {
        if (acc > u1) {
          if (acc > u0) { u3=u2;i3=i2; u2=u1;i2=i1; u1=u0;i1=i0; u0=acc;i0=j; }
          else          { u3=u2;i3=i2; u2=u1;i2=i1; u1=acc;i1=j; }
        } else {
          if (acc > u2) { u3=u2;i3=i2; u2=acc;i2=j; }
          else          { u3=acc;i3=j; }
        }
      }
    }
    // prefetch row t+2 into cb0 (wrap at end; wrapped loads are unused)
    {
      const int tp = (t + 2) & (C_PER - 1);
      #pragma unroll
      for (int q = 0; q < 8; ++q) cb0[q] = crow[tp * 8 + q];
    }
    // ---- center t+1 from cb1 ----
    {
      f32x2 a0 = 0.f, a1 = 0.f, a2 = 0.f, a3 = 0.f;
      #pragma unroll
      for (int q = 0; q < 8; ++q) {
        f32x2 c0 = {cb1[q].x, cb1[q].y};
        f32x2 c1 = {cb1[q].z, cb1[q].w};
        if (q & 1) {
          a2 = __builtin_elementwise_fma(xr[2 * q], c0, a2);
          a3 = __builtin_elementwise_fma(xr[2 * q + 1], c1, a3);
        } else {
          a0 = __builtin_elementwise_fma(xr[2 * q], c0, a0);
          a1 = __builtin_elementwise_fma(xr[2 * q + 1], c1, a1);
        }
      }
      f32x2 sA = a0 + a1, sB = a2 + a3, sT = sA + sB;
      const float acc = sT.x + sT.y - s_hcsq[t + 1];
      const int j = jbase + t + 1;
      if (acc > u3) {
        if (acc > u1) {
          if (acc > u0) { u3=u2;i3=i2; u2=u1;i2=i1; u1=u0;i1=i0; u0=acc;i0=j; }
          else          { u3=u2;i3=i2; u2=u1;i2=i1; u1=acc;i1=j; }
        } else {
          if (acc > u2) { u3=u2;i3=i2; u2=acc;i2=j; }
          else          { u3=acc;i3=j; }
        }
      }
    }
    // prefetch row t+3 into cb1
    {
      const int tp = (t + 3) & (C_PER - 1);
      #pragma unroll
      for (int q = 0; q < 8; ++q) cb1[q] = crow[tp * 8 + q];
    }
  }

  // per-lane result: contiguous 16B/lane writes
  float4 uo; uo.x = u0; uo.y = u1; uo.z = u2; uo.w = u3;
  int4   io; io.x = i0; io.y = i1; io.z = i2; io.w = i3;
  cu[(size_t)sp * N_SMPS + s] = uo;
  ci[(size_t)sp * N_SMPS + s] = io;
}

// ---------------- Kernel 1b: merge splits + fp64 refine ----------------------
#define KM_BLOCK 256

__global__ __launch_bounds__(KM_BLOCK) void k_merge(
    const float* __restrict__ x, const float* __restrict__ ctrs,
    const float4* __restrict__ cu, const int4* __restrict__ ci,
    int* __restrict__ idx_out)
{
  const int s = blockIdx.x * KM_BLOCK + threadIdx.x;

  float bu[8]; int bj[8];
  #pragma unroll
  for (int m = 0; m < 8; ++m) { bu[m] = -INFINITY; bj[m] = -1; }

  for (int sp = 0; sp < G_C; ++sp) {
    float4 u4 = cu[(size_t)sp * N_SMPS + s];
    int4   j4 = ci[(size_t)sp * N_SMPS + s];
    float uv[4] = {u4.x, u4.y, u4.z, u4.w};
    int   jv[4] = {j4.x, j4.y, j4.z, j4.w};
    #pragma unroll
    for (int q = 0; q < 4; ++q) {
      float u = uv[q]; int j = jv[q];
      if (u > bu[7]) {
        bu[7] = u; bj[7] = j;
        #pragma unroll
        for (int m = 7; m > 0; --m) {
          if (bu[m] > bu[m - 1]) {
            float tu = bu[m]; bu[m] = bu[m - 1]; bu[m - 1] = tu;
            int   tj = bj[m]; bj[m] = bj[m - 1]; bj[m - 1] = tj;
          }
        }
      }
    }
  }

  // reload x row
  float xr[D_IN];
  {
    const float4* xp = (const float4*)(x + (size_t)s * D_IN);
    #pragma unroll
    for (int q = 0; q < 8; ++q) {
      float4 v = xp[q];
      xr[4 * q + 0] = v.x; xr[4 * q + 1] = v.y;
      xr[4 * q + 2] = v.z; xr[4 * q + 3] = v.w;
    }
  }

  // exact fp64 squared distances on the 8 survivors (index tie-break = np)
  double bd[4]; int b4[4];
  #pragma unroll
  for (int m = 0; m < 4; ++m) { bd[m] = 1e300; b4[m] = 0x7fffffff; }
  for (int m = 0; m < 8; ++m) {
    int j = bj[m];
    const float* cp = ctrs + (size_t)j * D_IN;
    double d2 = 0.0;
    #pragma unroll
    for (int d = 0; d < D_IN; ++d) {
      double df = (double)xr[d] - (double)cp[d];
      d2 = fma(df, df, d2);
    }
    bool ins = (d2 < bd[3]) || (d2 == bd[3] && j < b4[3]);
    if (ins) {
      bd[3] = d2; b4[3] = j;
      #pragma unroll
      for (int q = 3; q > 0; --q) {
        bool sw = (bd[q] < bd[q - 1]) || (bd[q] == bd[q - 1] && b4[q] < b4[q - 1]);
        if (sw) {
          double td = bd[q]; bd[q] = bd[q - 1]; bd[q - 1] = td;
          int    tj = b4[q]; b4[q] = b4[q - 1]; b4[q - 1] = tj;
        }
      }
    }
  }
  #pragma unroll
  for (int q = 0; q < 4; ++q) idx_out[s * KNN + q] = b4[q];
}

// ---------------- Kernel 2: gather + apply local affine models ---------------
// (unchanged from R3 -- kept stable so its counters surface this round)
#define K2_BLOCK 256
#define K2_SAMPLES 8

__global__ __launch_bounds__(K2_BLOCK) void k_apply(
    const float* __restrict__ x, const float* __restrict__ ctrs,
    const float* __restrict__ wts, const float* __restrict__ offs,
    const int* __restrict__ idx, float* __restrict__ y)
{
  __shared__ float  s_diff[K2_SAMPLES][KNN][D_IN + 1];
  __shared__ float4 s_part[K2_SAMPLES][KNN][D_OUT / 4];
  const int tid = threadIdx.x;
  const int sbase = blockIdx.x * K2_SAMPLES;

  #pragma unroll
  for (int r = 0; r < K2_SAMPLES * KNN * D_IN / K2_BLOCK; ++r) {
    int v = r * K2_BLOCK + tid;
    int d = v & 31; int p = v >> 5;
    int sl = p >> 2; int j = p & 3;
    int f = idx[(sbase + sl) * KNN + j];
    s_diff[sl][j][d] =
        x[(size_t)(sbase + sl) * D_IN + d] - ctrs[(size_t)f * D_IN + d];
  }
  __syncthreads();

  const int sl = tid >> 5;
  const int j  = (tid >> 3) & 3;
  const int eq = tid & 7;
  const int s = sbase + sl;

  const int f = idx[s * KNN + j];
  const float4* wp = (const float4*)(wts + (size_t)f * (D_IN * D_OUT));
  float4 acc = ((const float4*)(offs + (size_t)f * D_OUT))[eq];
  #pragma unroll
  for (int d = 0; d < D_IN; ++d) {
    float4 wv = wp[d * (D_OUT / 4) + eq];
    float xc = s_diff[sl][j][d];
    acc.x = fmaf(xc, wv.x, acc.x);
    acc.y = fmaf(xc, wv.y, acc.y);
    acc.z = fmaf(xc, wv.z, acc.z);
    acc.w = fmaf(xc, wv.w, acc.w);
  }
  s_part[sl][j][eq] = acc;
  __syncthreads();

  if (j == 0) {
    float4 a = s_part[sl][0][eq], b = s_part[sl][1][eq];
    float4 c = s_part[sl][2][eq], e = s_part[sl][3][eq];
    float4 o;
    o.x = (a.x + b.x) + (c.x + e.x);
    o.y = (a.y + b.y) + (c.y + e.y);
    o.z = (a.z + b.z) + (c.z + e.z);
    o.w = (a.w + b.w) + (c.w + e.w);
    ((float4*)(y + (size_t)s * D_OUT))[eq] = o;
  }
}

// ---------------- launch -----------------------------------------------------
// ws layout: cu (16 splits x 16384 float4 = 4 MB) | ci (4 MB) | idx (256 KB)
// requires ws_size >= ~8.7 MB.
extern "C" void kernel_launch(void* const* d_in, const int* in_sizes, int n_in,
                              void* d_out, int out_size, void* d_ws, size_t ws_size,
                              hipStream_t stream) {
  const float* x    = (const float*)d_in[0];
  const float* ctrs = (const float*)d_in[1];
  const float* wts  = (const float*)d_in[2];
  const float* offs = (const float*)d_in[3];
  float* y = (float*)d_out;

  float4* cu  = (float4*)d_ws;
  int4*   ci  = (int4*)((char*)d_ws + (size_t)G_C * N_SMPS * sizeof(float4));
  int*   idxb = (int*)((char*)d_ws + (size_t)2 * G_C * N_SMPS * sizeof(float4));

  k_topk<<<(N_SMPS / K1_BLOCK) * G_C, K1_BLOCK, 0, stream>>>(x, ctrs, cu, ci);
  k_merge<<<N_SMPS / KM_BLOCK, KM_BLOCK, 0, stream>>>(x, ctrs, cu, ci, idxb);
  k_apply<<<N_SMPS / K2_SAMPLES, K2_BLOCK, 0, stream>>>(x, ctrs, wts, offs,
                                                        idxb, y);
}

// Round 6
// 135.436 us; speedup vs baseline: 1.4825x; 1.4825x over previous
//
#include <hip/hip_runtime.h>
#include <math.h>

typedef short bf16x8 __attribute__((ext_vector_type(8)));
typedef float f32x4  __attribute__((ext_vector_type(4)));
typedef unsigned short ushort_t;

#define N_SMPS 16384
#define N_FCNS 2048
#define D_IN 32
#define D_OUT 32
#define KNN 4
#define SPLITS 4
#define CPS 512            // centers per split
#define TILES 32           // CPS / 16

__device__ __forceinline__ unsigned umin_u(unsigned a, unsigned b) { return a < b ? a : b; }
__device__ __forceinline__ unsigned umax_u(unsigned a, unsigned b) { return a > b ? a : b; }

// round-to-nearest-even fp32 -> bf16
__device__ __forceinline__ ushort_t bf16_rne(float f) {
  unsigned b = __float_as_uint(f);
  unsigned r = b + 0x7FFFu + ((b >> 16) & 1u);
  return (ushort_t)(r >> 16);
}

// ---------------- ws layout (bytes) ------------------------------------------
// xh 1MB | xl 1MB | ch 128K | cl 128K | hb 8K | cand 2MB (8 u32 slots, 6 used)
// | idx 256K   -> total ~4.5 MB
#define OFF_XH   0u
#define OFF_XL   (1u << 20)
#define OFF_CH   (2u << 20)
#define OFF_CL   (OFF_CH + 131072u)
#define OFF_HB   (OFF_CL + 131072u)
#define OFF_CAND (OFF_HB + 8192u)
#define OFF_IDX  (OFF_CAND + (SPLITS * N_SMPS * 32u))

// ---------------- Kernel 0: bf16 hi/lo split (RNE) + center half-norms -------
__global__ __launch_bounds__(256) void k_prep(
    const float* __restrict__ x, const float* __restrict__ ctrs,
    ushort_t* __restrict__ xh, ushort_t* __restrict__ xl,
    ushort_t* __restrict__ ch, ushort_t* __restrict__ cl,
    float* __restrict__ hb)
{
  const int gt = blockIdx.x * 256 + threadIdx.x;
  const int NX4 = N_SMPS * D_IN / 4;   // 131072
  const int NC4 = N_FCNS * D_IN / 4;   // 16384

  const float* src; ushort_t* dh; ushort_t* dl; int i4;
  if (gt < NX4) { src = x; dh = xh; dl = xl; i4 = gt; }
  else          { src = ctrs; dh = ch; dl = cl; i4 = gt - NX4; }
  if (gt < NX4 + NC4) {
    float4 v = ((const float4*)src)[i4];
    float vv[4] = {v.x, v.y, v.z, v.w};
    ushort_t h[4], l[4];
    #pragma unroll
    for (int q = 0; q < 4; ++q) {
      ushort_t hh = bf16_rne(vv[q]);
      float hf = __uint_as_float(((unsigned)hh) << 16);
      h[q] = hh;
      l[q] = bf16_rne(vv[q] - hf);
    }
    ushort_t* ph = dh + 4 * i4; ushort_t* pl = dl + 4 * i4;
    #pragma unroll
    for (int q = 0; q < 4; ++q) { ph[q] = h[q]; pl[q] = l[q]; }
  }
  if (gt < N_FCNS) {
    const float4* cp4 = (const float4*)(ctrs + (size_t)gt * D_IN);
    float a = 0.f;
    #pragma unroll
    for (int q = 0; q < 8; ++q) {
      float4 v = cp4[q];
      a += v.x * v.x + v.y * v.y + v.z * v.z + v.w * v.w;
    }
    hb[gt] = -0.5f * a;   // NO bias: scores stay near 0 magnitude
  }
}

// ---------------- Kernel 1: MFMA scores + packed-key top-6 per split ---------
// Block = 256 thr = 4 waves; wave w = split w (512 centers, 32 tiles of 16)
// x 16 samples. 4 MFMAs/tile (hh,hl,lh,ll). Keys: monotone u32 of fp32 score
// with low 9 bits = within-split center id (quant ~1e-3, margins absorb it).
__global__ __launch_bounds__(256, 4) void k_topk(
    const ushort_t* __restrict__ xh, const ushort_t* __restrict__ xl,
    const ushort_t* __restrict__ ch, const ushort_t* __restrict__ cl,
    const float* __restrict__ hb, unsigned* __restrict__ cand)
{
  __shared__ unsigned s_mrg[4][16 * 68];   // [wave][row*68 + col*4 + e]

  const int tid = threadIdx.x;
  const int lane = tid & 63;
  const int w = __builtin_amdgcn_readfirstlane(tid >> 6);  // wave = split
  const int col = lane & 15;
  const int quad = lane >> 4;
  const int sbase = blockIdx.x * 16;
  const int nbase0 = w * CPS;

  // A-frag: lane holds A[m=col][k=quad*8+j], 16 B contiguous
  const bf16x8 ah = *(const bf16x8*)(xh + (size_t)(sbase + col) * D_IN + quad * 8);
  const bf16x8 al = *(const bf16x8*)(xl + (size_t)(sbase + col) * D_IN + quad * 8);

  unsigned ls[4][4];
  #pragma unroll
  for (int r = 0; r < 4; ++r)
    #pragma unroll
    for (int e = 0; e < 4; ++e) ls[r][e] = 0u;   // real keys always > 0

  #pragma unroll 2
  for (int t = 0; t < TILES; ++t) {
    const int nb = nbase0 + t * 16;
    // B-frag: lane holds B[k=quad*8+j][n=col] = ctr[nb+col][quad*8+j]
    const bf16x8 bh = *(const bf16x8*)(ch + (size_t)(nb + col) * D_IN + quad * 8);
    const bf16x8 bl = *(const bf16x8*)(cl + (size_t)(nb + col) * D_IN + quad * 8);
    const float hbv = hb[nb + col];
    f32x4 acc = {0.f, 0.f, 0.f, 0.f};        // pure dot: max fp32 accuracy
    acc = __builtin_amdgcn_mfma_f32_16x16x32_bf16(ah, bh, acc, 0, 0, 0);
    acc = __builtin_amdgcn_mfma_f32_16x16x32_bf16(ah, bl, acc, 0, 0, 0);
    acc = __builtin_amdgcn_mfma_f32_16x16x32_bf16(al, bh, acc, 0, 0, 0);
    acc = __builtin_amdgcn_mfma_f32_16x16x32_bf16(al, bl, acc, 0, 0, 0);
    const unsigned tc = (unsigned)(t * 16 + col);   // 9-bit local center id
    #pragma unroll
    for (int r = 0; r < 4; ++r) {
      const float u = acc[r] + hbv;                 // score (maximize)
      unsigned b = __float_as_uint(u);
      unsigned m = b ^ ((unsigned)((int)b >> 31) | 0x80000000u);  // monotone
      unsigned key = (m & 0xFFFFFE00u) | tc;
      unsigned t0 = umin_u(ls[r][0], key); ls[r][0] = umax_u(ls[r][0], key);
      unsigned t1 = umin_u(ls[r][1], t0);  ls[r][1] = umax_u(ls[r][1], t0);
      unsigned t2 = umin_u(ls[r][2], t1);  ls[r][2] = umax_u(ls[r][2], t1);
      ls[r][3] = umax_u(ls[r][3], t2);
    }
  }

  // stage per-(row,col) top-4 (keys are self-contained: 9-bit id in low bits)
  unsigned* mrg = s_mrg[w];
  #pragma unroll
  for (int r = 0; r < 4; ++r) {
    const int row = quad * 4 + r;
    *(uint4*)(mrg + row * 68 + col * 4) =
        make_uint4(ls[r][0], ls[r][1], ls[r][2], ls[r][3]);
  }
  __syncthreads();

  // lanes<16: merge 64 keys of row=lane -> split top-6
  if (lane < 16) {
    unsigned q0 = 0, q1 = 0, q2 = 0, q3 = 0, q4 = 0, q5 = 0;
    const uint4* rp = (const uint4*)(mrg + lane * 68);
    #pragma unroll
    for (int c2 = 0; c2 < 16; ++c2) {
      uint4 kv = rp[c2];
      unsigned ks[4] = {kv.x, kv.y, kv.z, kv.w};
      #pragma unroll
      for (int e = 0; e < 4; ++e) {
        unsigned key = ks[e];
        unsigned t0 = umin_u(q0, key); q0 = umax_u(q0, key);
        unsigned t1 = umin_u(q1, t0);  q1 = umax_u(q1, t0);
        unsigned t2 = umin_u(q2, t1);  q2 = umax_u(q2, t1);
        unsigned t3 = umin_u(q3, t2);  q3 = umax_u(q3, t2);
        unsigned t4 = umin_u(q4, t3);  q4 = umax_u(q4, t3);
        q5 = umax_u(q5, t4);
      }
    }
    unsigned* op = cand + ((size_t)w * N_SMPS + sbase + lane) * 8;
    *(uint4*)op = make_uint4(q0, q1, q2, q3);
    *(uint2*)(op + 4) = make_uint2(q4, q5);
  }
}

// ---------------- Kernel 1b: fp64-exact top-4 over the 24-candidate pool -----
#define KM_BLOCK 128

__global__ __launch_bounds__(KM_BLOCK) void k_merge(
    const float* __restrict__ x, const float* __restrict__ ctrs,
    const unsigned* __restrict__ cand, int* __restrict__ idx_out)
{
  const int s = blockIdx.x * KM_BLOCK + threadIdx.x;

  int nn[SPLITS * 6];
  #pragma unroll
  for (int sp = 0; sp < SPLITS; ++sp) {
    const unsigned* ip = cand + ((size_t)sp * N_SMPS + s) * 8;
    uint4 a = *(const uint4*)ip;
    uint2 b = *(const uint2*)(ip + 4);
    nn[sp * 6 + 0] = sp * CPS + (int)(a.x & 0x1FFu);
    nn[sp * 6 + 1] = sp * CPS + (int)(a.y & 0x1FFu);
    nn[sp * 6 + 2] = sp * CPS + (int)(a.z & 0x1FFu);
    nn[sp * 6 + 3] = sp * CPS + (int)(a.w & 0x1FFu);
    nn[sp * 6 + 4] = sp * CPS + (int)(b.x & 0x1FFu);
    nn[sp * 6 + 5] = sp * CPS + (int)(b.y & 0x1FFu);
  }

  // x row in double (exact)
  double xd[D_IN];
  {
    const float4* xp = (const float4*)(x + (size_t)s * D_IN);
    #pragma unroll
    for (int q = 0; q < 8; ++q) {
      float4 v = xp[q];
      xd[4 * q + 0] = (double)v.x; xd[4 * q + 1] = (double)v.y;
      xd[4 * q + 2] = (double)v.z; xd[4 * q + 3] = (double)v.w;
    }
  }

  // exact fp64 squared distance, top-4 with np-stable tie-break (lower idx)
  double bd[4]; int b4[4];
  #pragma unroll
  for (int e = 0; e < 4; ++e) { bd[e] = 1e300; b4[e] = 0x7fffffff; }
  for (int m = 0; m < SPLITS * 6; ++m) {
    const int j = nn[m];
    const float* cp = ctrs + (size_t)j * D_IN;
    double d2a = 0.0, d2b = 0.0;
    #pragma unroll
    for (int d = 0; d < D_IN; d += 2) {
      double df0 = xd[d] - (double)cp[d];
      double df1 = xd[d + 1] - (double)cp[d + 1];
      d2a = fma(df0, df0, d2a);
      d2b = fma(df1, df1, d2b);
    }
    double d2 = d2a + d2b;
    bool ins = (d2 < bd[3]) || (d2 == bd[3] && j < b4[3]);
    if (ins) {
      bd[3] = d2; b4[3] = j;
      #pragma unroll
      for (int q = 3; q > 0; --q) {
        bool sw = (bd[q] < bd[q - 1]) || (bd[q] == bd[q - 1] && b4[q] < b4[q - 1]);
        if (sw) {
          double td = bd[q]; bd[q] = bd[q - 1]; bd[q - 1] = td;
          int    tj = b4[q]; b4[q] = b4[q - 1]; b4[q - 1] = tj;
        }
      }
    }
  }
  #pragma unroll
  for (int q = 0; q < 4; ++q) idx_out[s * KNN + q] = b4[q];
}

// ---------------- Kernel 2: gather + apply local affine models ---------------
// (unchanged -- kept stable so its counters surface this round)
#define K2_BLOCK 256
#define K2_SAMPLES 8

__global__ __launch_bounds__(K2_BLOCK) void k_apply(
    const float* __restrict__ x, const float* __restrict__ ctrs,
    const float* __restrict__ wts, const float* __restrict__ offs,
    const int* __restrict__ idx, float* __restrict__ y)
{
  __shared__ float  s_diff[K2_SAMPLES][KNN][D_IN + 1];
  __shared__ float4 s_part[K2_SAMPLES][KNN][D_OUT / 4];
  const int tid = threadIdx.x;
  const int sbase = blockIdx.x * K2_SAMPLES;

  #pragma unroll
  for (int r = 0; r < K2_SAMPLES * KNN * D_IN / K2_BLOCK; ++r) {
    int v = r * K2_BLOCK + tid;
    int d = v & 31; int p = v >> 5;
    int sl = p >> 2; int j = p & 3;
    int f = idx[(sbase + sl) * KNN + j];
    s_diff[sl][j][d] =
        x[(size_t)(sbase + sl) * D_IN + d] - ctrs[(size_t)f * D_IN + d];
  }
  __syncthreads();

  const int sl = tid >> 5;
  const int j  = (tid >> 3) & 3;
  const int eq = tid & 7;
  const int s = sbase + sl;

  const int f = idx[s * KNN + j];
  const float4* wp = (const float4*)(wts + (size_t)f * (D_IN * D_OUT));
  float4 acc = ((const float4*)(offs + (size_t)f * D_OUT))[eq];
  #pragma unroll
  for (int d = 0; d < D_IN; ++d) {
    float4 wv = wp[d * (D_OUT / 4) + eq];
    float xc = s_diff[sl][j][d];
    acc.x = fmaf(xc, wv.x, acc.x);
    acc.y = fmaf(xc, wv.y, acc.y);
    acc.z = fmaf(xc, wv.z, acc.z);
    acc.w = fmaf(xc, wv.w, acc.w);
  }
  s_part[sl][j][eq] = acc;
  __syncthreads();

  if (j == 0) {
    float4 a = s_part[sl][0][eq], b = s_part[sl][1][eq];
    float4 c = s_part[sl][2][eq], e = s_part[sl][3][eq];
    float4 o;
    o.x = (a.x + b.x) + (c.x + e.x);
    o.y = (a.y + b.y) + (c.y + e.y);
    o.z = (a.z + b.z) + (c.z + e.z);
    o.w = (a.w + b.w) + (c.w + e.w);
    ((float4*)(y + (size_t)s * D_OUT))[eq] = o;
  }
}

// ---------------- launch -----------------------------------------------------
extern "C" void kernel_launch(void* const* d_in, const int* in_sizes, int n_in,
                              void* d_out, int out_size, void* d_ws, size_t ws_size,
                              hipStream_t stream) {
  const float* x    = (const float*)d_in[0];
  const float* ctrs = (const float*)d_in[1];
  const float* wts  = (const float*)d_in[2];
  const float* offs = (const float*)d_in[3];
  float* y = (float*)d_out;

  char* ws = (char*)d_ws;
  ushort_t* xh = (ushort_t*)(ws + OFF_XH);
  ushort_t* xl = (ushort_t*)(ws + OFF_XL);
  ushort_t* ch = (ushort_t*)(ws + OFF_CH);
  ushort_t* cl = (ushort_t*)(ws + OFF_CL);
  float*    hb = (float*)(ws + OFF_HB);
  unsigned* cand = (unsigned*)(ws + OFF_CAND);
  int*    idxb = (int*)(ws + OFF_IDX);

  k_prep<<<(N_SMPS * D_IN / 4 + N_FCNS * D_IN / 4) / 256, 256, 0, stream>>>(
      x, ctrs, xh, xl, ch, cl, hb);
  k_topk<<<N_SMPS / 16, 256, 0, stream>>>(xh, xl, ch, cl, hb, cand);
  k_merge<<<N_SMPS / KM_BLOCK, KM_BLOCK, 0, stream>>>(x, ctrs, cand, idxb);
  k_apply<<<N_SMPS / K2_SAMPLES, K2_BLOCK, 0, stream>>>(x, ctrs, wts, offs,
                                                        idxb, y);
}